// Round 1
// baseline (27646.341 us; speedup 1.0000x reference)
//
#include <hip/hip_runtime.h>
#include <math.h>

#define B_ 16
#define T_ 64
#define DETER_ 4096
#define STOCH_ 512
#define UNITS_ 1024
#define EMBED_ 4096
#define FOUT_ 11264

enum { JOB_IMGIN=0, JOB_GATES=1, JOB_PRIOR=2, JOB_OBS=3, JOB_PRIOR_INIT=4 };

struct SP {
  const float* embed; const float* action; const int* is_first;
  const float* wpad_imgin; const float* b_imgin;
  const float* w_ih; const float* w_hh; const float* b_ih; const float* b_hh;
  const float* w_imgout; const float* b_imgout;
  const float* w_obs; const float* b_obs;
  const float* eps_prior; const float* eps_post;
  const float* deter_in; float* deter_out; const float* dnew;
  float* stoch; float* x_img; float* out;
  int t;
};

__device__ __forceinline__ float4 ld4(const float* p){ return *reinterpret_cast<const float4*>(p); }
__device__ __forceinline__ float sigm(float x){ return 1.f/(1.f+expf(-x)); }

// Generic B=16 skinny matmul body. Block = 256 threads (4 waves).
// Rows/block: 8 (12 for gates: 3 gates x 4 units). X staged in LDS 1024-float chunks.
// Weights streamed from global as float4 (the HBM-bound stream). Epilogue fused per job.
template<int JOB>
__device__ __forceinline__ void mv_body(const SP& p, int bid, float* Xs) {
  constexpr int RW   = (JOB==JOB_GATES)?3:2;                 // rows per wave
  constexpr int KTOT = (JOB==JOB_IMGIN)?1024:((JOB==JOB_GATES)?5120:((JOB==JOB_OBS)?8192:4096));
  constexpr int CHUNKS = KTOT/1024;
  const int tid = threadIdx.x;
  const int wave = tid>>6, lane = tid&63;
  const int t = p.t;

  float acc[RW][16];
  float accH[(JOB==JOB_GATES)?3:1][16];   // h-part accumulators (gates only)
  #pragma unroll
  for (int r=0;r<RW;++r)
    #pragma unroll
    for (int b=0;b<16;++b) acc[r][b]=0.f;
  if constexpr (JOB==JOB_GATES) {
    #pragma unroll
    for (int r=0;r<3;++r)
      #pragma unroll
      for (int b=0;b<16;++b) accH[r][b]=0.f;
  }

  int rowIdx[RW];
  #pragma unroll
  for (int r=0;r<RW;++r) {
    int rl = wave*RW + r;
    if constexpr (JOB==JOB_IMGIN || JOB==JOB_PRIOR_INIT) rowIdx[r] = bid*8 + rl;
    else if constexpr (JOB==JOB_GATES) rowIdx[r] = r*DETER_ + bid*4 + wave;   // gate r of unit j=bid*4+wave
    else rowIdx[r] = (rl<4) ? (bid*4+rl) : (512 + bid*4 + (rl-4));            // mean rows then std rows
  }

  const int kc = tid*4;   // this thread's float4 within a 1024-float chunk row
  for (int c=0;c<CHUNKS;++c) {
    __syncthreads();
    // ---- stage X chunk into LDS (one float4 per thread per batch row) ----
    #pragma unroll
    for (int b=0;b<16;++b) {
      float4 v;
      if constexpr (JOB==JOB_IMGIN) {
        float mb = p.is_first[b*T_+t] ? 0.f : 1.f;
        if (kc < 512) { v = ld4(p.stoch + b*STOCH_ + kc); v.x*=mb; v.y*=mb; v.z*=mb; v.w*=mb; }
        else if (kc == 512) {
          const float* ap = p.action + (b*T_+t)*2;
          float a0 = ap[0], a1 = ap[1];
          a0 = a0 / fmaxf(fabsf(a0),1.f);       // ACTION_CLIP=1
          a1 = a1 / fmaxf(fabsf(a1),1.f);
          v = make_float4(a0*mb, a1*mb, 0.f, 0.f);
        } else v = make_float4(0.f,0.f,0.f,0.f);
      } else if constexpr (JOB==JOB_GATES) {
        if (c==0) v = ld4(p.x_img + b*UNITS_ + kc);
        else {
          float mb = p.is_first[b*T_+t] ? 0.f : 1.f;
          v = ld4(p.deter_in + b*DETER_ + (c-1)*1024 + kc);
          v.x*=mb; v.y*=mb; v.z*=mb; v.w*=mb;
        }
      } else if constexpr (JOB==JOB_PRIOR || JOB==JOB_PRIOR_INIT) {
        v = ld4(p.dnew + b*DETER_ + c*1024 + kc);
      } else { // JOB_OBS: concat(d_new, embed_t)
        if (c<4) v = ld4(p.dnew + b*DETER_ + c*1024 + kc);
        else     v = ld4(p.embed + ((size_t)(b*T_+t))*EMBED_ + (c-4)*1024 + kc);
      }
      *reinterpret_cast<float4*>(Xs + b*1024 + kc) = v;
    }
    __syncthreads();

    // ---- weight base pointers for this chunk ----
    const float* wb[RW];
    #pragma unroll
    for (int r=0;r<RW;++r) {
      if constexpr (JOB==JOB_IMGIN)
        wb[r] = p.wpad_imgin + (size_t)rowIdx[r]*1024;
      else if constexpr (JOB==JOB_GATES)
        wb[r] = (c==0) ? (p.w_ih + (size_t)rowIdx[r]*1024)
                       : (p.w_hh + (size_t)rowIdx[r]*4096 + (size_t)(c-1)*1024);
      else if constexpr (JOB==JOB_PRIOR || JOB==JOB_PRIOR_INIT)
        wb[r] = p.w_imgout + (size_t)rowIdx[r]*4096 + (size_t)c*1024;
      else
        wb[r] = p.w_obs + (size_t)rowIdx[r]*8192 + (size_t)c*1024;
    }

    auto inner = [&](float (&A)[RW][16]) {
      #pragma unroll
      for (int it=0; it<4; ++it) {
        const int k0 = it*256 + lane*4;
        float4 w4[RW];
        #pragma unroll
        for (int r=0;r<RW;++r) w4[r] = ld4(wb[r] + k0);
        #pragma unroll
        for (int b=0;b<16;++b) {
          float4 xv = ld4(Xs + b*1024 + k0);   // linear ds_read_b128, conflict-free
          #pragma unroll
          for (int r=0;r<RW;++r)
            A[r][b] += w4[r].x*xv.x + w4[r].y*xv.y + w4[r].z*xv.z + w4[r].w*xv.w;
        }
      }
    };
    if constexpr (JOB==JOB_GATES) { if (c==0) inner(acc); else inner(accH); }
    else inner(acc);
  }

  // ---- cross-lane reduction (each lane holds a k-partial) ----
  if constexpr (JOB==JOB_GATES) {
    #pragma unroll
    for (int b=0;b<16;++b){ acc[0][b]+=accH[0][b]; acc[1][b]+=accH[1][b]; } // r,z gates only need the sum
    #pragma unroll
    for (int off=1; off<64; off<<=1) {
      #pragma unroll
      for (int b=0;b<16;++b) {
        acc[0][b]  += __shfl_xor(acc[0][b],  off);
        acc[1][b]  += __shfl_xor(acc[1][b],  off);
        acc[2][b]  += __shfl_xor(acc[2][b],  off);   // n gate, x part
        accH[2][b] += __shfl_xor(accH[2][b], off);   // n gate, h part
      }
    }
    __syncthreads();           // all Xs reads done -> safe to overlay results
    if (lane==0) {
      #pragma unroll
      for (int b=0;b<16;++b) {
        Xs[(wave*4+0)*16+b] = acc[0][b];
        Xs[(wave*4+1)*16+b] = acc[1][b];
        Xs[(wave*4+2)*16+b] = acc[2][b];
        Xs[(wave*4+3)*16+b] = accH[2][b];
      }
    }
  } else {
    #pragma unroll
    for (int off=1; off<64; off<<=1)
      #pragma unroll
      for (int r=0;r<RW;++r)
        #pragma unroll
        for (int b=0;b<16;++b)
          acc[r][b] += __shfl_xor(acc[r][b], off);
    __syncthreads();
    if (lane==0) {
      #pragma unroll
      for (int r=0;r<RW;++r)
        #pragma unroll
        for (int b=0;b<16;++b)
          Xs[(wave*RW+r)*16+b] = acc[r][b];
    }
  }
  __syncthreads();
  const float* res = Xs;

  // ---- fused epilogues ----
  if constexpr (JOB==JOB_GATES) {
    if (tid < 64) {
      int w = tid>>4, b = tid&15;
      int j = bid*4 + w;
      float rs = res[(w*4+0)*16+b] + p.b_ih[j]          + p.b_hh[j];
      float zs = res[(w*4+1)*16+b] + p.b_ih[DETER_+j]   + p.b_hh[DETER_+j];
      float ni = res[(w*4+2)*16+b] + p.b_ih[2*DETER_+j];
      float nh = res[(w*4+3)*16+b] + p.b_hh[2*DETER_+j];
      float rg = sigm(rs), zg = sigm(zs);
      float ng = tanhf(ni + rg*nh);
      float mb = p.is_first[b*T_+t] ? 0.f : 1.f;
      float hp = p.deter_in[b*DETER_+j] * mb;
      float d  = (1.f-zg)*ng + zg*hp;
      p.deter_out[b*DETER_+j] = d;
      size_t ob = ((size_t)(b*T_+t))*FOUT_;
      p.out[ob+1536+j] = d;
      p.out[ob+7168+j] = d;
    }
  } else if constexpr (JOB==JOB_PRIOR) {
    if (tid < 64) {
      int rl = tid>>4, b = tid&15;
      int j = bid*4 + rl;
      float mean = res[rl*16+b]     + p.b_imgout[j];
      float sr   = res[(rl+4)*16+b] + p.b_imgout[512+j];
      float sd = 2.f*sigm(sr*0.5f) + 0.1f; sd = fmaxf(sd, 1e-4f);
      float ep = p.eps_prior[((size_t)t*B_+b)*STOCH_ + j];
      size_t ob = ((size_t)(b*T_+t))*FOUT_;
      p.out[ob+5632+j] = fmaf(sd, ep, mean);
      p.out[ob+6144+j] = mean;
      p.out[ob+6656+j] = sd;
    }
  } else if constexpr (JOB==JOB_OBS) {
    if (tid < 64) {
      int rl = tid>>4, b = tid&15;
      int j = bid*4 + rl;
      float mean = res[rl*16+b]     + p.b_obs[j];
      float sr   = res[(rl+4)*16+b] + p.b_obs[512+j];
      float sd = 2.f*sigm(sr*0.5f) + 0.1f; sd = fmaxf(sd, 1e-4f);
      float eo = p.eps_post[((size_t)t*B_+b)*STOCH_ + j];
      float ost = fmaf(sd, eo, mean);
      size_t ob = ((size_t)(b*T_+t))*FOUT_;
      p.out[ob+0+j]    = ost;
      p.out[ob+512+j]  = mean;
      p.out[ob+1024+j] = sd;
      p.stoch[b*STOCH_+j] = ost;        // carry for next step
    }
  } else if constexpr (JOB==JOB_IMGIN) {
    if (tid < 128) {
      int rl = tid>>4, b = tid&15;
      int row = bid*8 + rl;
      p.x_img[b*UNITS_+row] = res[rl*16+b] + p.b_imgin[row];
    }
  } else { // JOB_PRIOR_INIT: stoch0 = mean part only
    if (tid < 128) {
      int rl = tid>>4, b = tid&15;
      int row = bid*8 + rl;          // row < 512 (mean rows)
      p.stoch[b*STOCH_+row] = res[rl*16+b] + p.b_imgout[row];
    }
  }
}

template<int JOB>
__global__ __launch_bounds__(256,2) void mv_single(SP p) {
  __shared__ float Xs[16*1024];
  mv_body<JOB>(p, blockIdx.x, Xs);
}

// prior (128 blocks) + obs (128 blocks) in one launch
__global__ __launch_bounds__(256,2) void post_kernel(SP p) {
  __shared__ float Xs[16*1024];
  if (blockIdx.x < 128) mv_body<JOB_PRIOR>(p, blockIdx.x, Xs);
  else                  mv_body<JOB_OBS>(p, blockIdx.x - 128, Xs);
}

__global__ void pad_imgin_kernel(const float* w, float* wpad) {
  int row = blockIdx.x;
  for (int k=threadIdx.x; k<1024; k+=256)
    wpad[row*1024+k] = (k<514) ? w[row*514+k] : 0.f;
}

__global__ void init_deter_kernel(const float* ini, float* det) {
  int k = blockIdx.x*256 + threadIdx.x;
  float v = tanhf(ini[k]);
  #pragma unroll
  for (int b=0;b<16;++b) det[b*DETER_+k] = v;
}

extern "C" void kernel_launch(void* const* d_in, const int* in_sizes, int n_in,
                              void* d_out, int out_size, void* d_ws, size_t ws_size,
                              hipStream_t stream) {
  (void)in_sizes; (void)n_in; (void)out_size; (void)ws_size;
  SP p;
  p.embed     = (const float*)d_in[0];
  p.action    = (const float*)d_in[1];
  p.is_first  = (const int*)  d_in[2];
  const float* initial_deter = (const float*)d_in[3];
  p.w_obs     = (const float*)d_in[4];
  p.b_obs     = (const float*)d_in[5];
  const float* w_imgin       = (const float*)d_in[6];
  p.b_imgin   = (const float*)d_in[7];
  p.w_imgout  = (const float*)d_in[8];
  p.b_imgout  = (const float*)d_in[9];
  p.w_ih      = (const float*)d_in[10];
  p.w_hh      = (const float*)d_in[11];
  p.b_ih      = (const float*)d_in[12];
  p.b_hh      = (const float*)d_in[13];
  p.eps_prior = (const float*)d_in[14];
  p.eps_post  = (const float*)d_in[15];
  p.out = (float*)d_out;

  // ws layout (floats): wpad 1M | deterA 64K | deterB 64K | stoch 8K | x_img 16K  (~4.8 MB)
  float* ws     = (float*)d_ws;
  float* wpad   = ws;
  float* deterA = wpad   + 1024*1024;
  float* deterB = deterA + 16*DETER_;
  float* stoch  = deterB + 16*DETER_;
  float* ximg   = stoch  + 16*STOCH_;
  p.wpad_imgin = wpad;
  p.stoch = stoch;
  p.x_img = ximg;

  pad_imgin_kernel<<<1024,256,0,stream>>>(w_imgin, wpad);
  init_deter_kernel<<<DETER_/256,256,0,stream>>>(initial_deter, deterA);

  // stoch0 = mean(stats(deter0 @ w_imgout.T + b))
  p.t = 0; p.deter_in = deterA; p.deter_out = deterB; p.dnew = deterA;
  mv_single<JOB_PRIOR_INIT><<<64,256,0,stream>>>(p);

  for (int t=0; t<T_; ++t) {
    p.t = t;
    p.deter_in  = (t&1) ? deterB : deterA;
    p.deter_out = (t&1) ? deterA : deterB;
    p.dnew      = p.deter_out;
    mv_single<JOB_IMGIN><<<128,256,0,stream>>>(p);   // x_img = imgin(concat(stoch_m, a_m))
    mv_single<JOB_GATES><<<1024,256,0,stream>>>(p);  // GRU fused: gi,gh matmuls + gates + d_new (+out copies)
    post_kernel<<<256,256,0,stream>>>(p);            // prior + obs matmuls + stats + rsample + out
  }
}

// Round 2
// 15265.390 us; speedup vs baseline: 1.8110x; 1.8110x over previous
//
#include <hip/hip_runtime.h>
#include <math.h>

#define B_ 16
#define T_ 64
#define DETER_ 4096
#define STOCH_ 512
#define UNITS_ 1024
#define EMBED_ 4096
#define FOUT_ 11264

enum { JOB_IMGIN=0, JOB_GATES=1, JOB_PRIOR=2, JOB_OBS=3, JOB_PRIOR_INIT=4 };

struct SP {
  const float* embed; const float* action; const int* is_first;
  const float* wpad_imgin; const float* b_imgin;
  const float* w_ih; const float* w_hh; const float* b_ih; const float* b_hh;
  const float* w_imgout; const float* b_imgout;
  const float* w_obs; const float* b_obs;
  const float* eps_prior; const float* eps_post;
  const float* deter_in; float* deter_out; const float* dnew;
  float* stoch; float* x_img; float* out;
  int t;
};

__device__ __forceinline__ float4 ld4(const float* p){ return *reinterpret_cast<const float4*>(p); }
__device__ __forceinline__ float sigm(float x){ return 1.f/(1.f+expf(-x)); }
__device__ __forceinline__ float dot4(float4 w, float4 x, float a){
  return fmaf(w.x,x.x, fmaf(w.y,x.y, fmaf(w.z,x.z, fmaf(w.w,x.w, a))));
}

// Stage one 1024-float K-chunk of X for all 16 batches into LDS.
// Each thread writes one float4 per batch row (linear, conflict-free).
template<int JOB>
__device__ __forceinline__ void stage_chunk(const SP& p, float* Xs, int c, int kc, int t) {
  __syncthreads();
  #pragma unroll
  for (int b=0;b<16;++b) {
    float4 v;
    if constexpr (JOB==JOB_IMGIN) {
      float mb = p.is_first[b*T_+t] ? 0.f : 1.f;
      if (kc < 512) { v = ld4(p.stoch + b*STOCH_ + kc); v.x*=mb; v.y*=mb; v.z*=mb; v.w*=mb; }
      else if (kc == 512) {
        const float* ap = p.action + (b*T_+t)*2;
        float a0 = ap[0], a1 = ap[1];
        a0 = a0 / fmaxf(fabsf(a0),1.f);       // ACTION_CLIP=1
        a1 = a1 / fmaxf(fabsf(a1),1.f);
        v = make_float4(a0*mb, a1*mb, 0.f, 0.f);
      } else v = make_float4(0.f,0.f,0.f,0.f);
    } else if constexpr (JOB==JOB_GATES) {
      if (c==0) v = ld4(p.x_img + b*UNITS_ + kc);
      else {
        float mb = p.is_first[b*T_+t] ? 0.f : 1.f;
        v = ld4(p.deter_in + b*DETER_ + (c-1)*1024 + kc);
        v.x*=mb; v.y*=mb; v.z*=mb; v.w*=mb;
      }
    } else if constexpr (JOB==JOB_PRIOR || JOB==JOB_PRIOR_INIT) {
      v = ld4(p.dnew + b*DETER_ + c*1024 + kc);
    } else { // JOB_OBS: concat(d_new, embed_t)
      if (c<4) v = ld4(p.dnew + b*DETER_ + c*1024 + kc);
      else     v = ld4(p.embed + ((size_t)(b*T_+t))*EMBED_ + (c-4)*1024 + kc);
    }
    *reinterpret_cast<float4*>(Xs + b*1024 + kc) = v;
  }
  __syncthreads();
}

// ---------------- GATES: GRU fused ----------------
// Block = 256 thr / 4 waves; each wave owns one unit j = bid*4 + wave.
// Batch-split: lanes 0-31 accumulate batches 0-7, lanes 32-63 batches 8-15.
// r,z gates accumulate x-part + h-part into the SAME register (only n needs split).
// Per-thread live state: 4 arrays x 8 f32 = 32 accumulators (was 96 -> spilled).
__device__ __forceinline__ void gates_body(const SP& p, int bid, float* Xs) {
  const int tid = threadIdx.x;
  const int wave = tid>>6, lane = tid&63;
  const int half = lane>>5, sl = lane&31;
  const int t = p.t;
  const int kc = tid*4;
  const int j = bid*4 + wave;

  float ar[8], az[8], anx[8], anh[8];
  #pragma unroll
  for (int b=0;b<8;++b){ ar[b]=0.f; az[b]=0.f; anx[b]=0.f; anh[b]=0.f; }

#define GATES_INNER(WR,WZ,WN,AN)                                           \
  _Pragma("unroll")                                                        \
  for (int it=0; it<8; ++it) {                                             \
    const int k0 = it*128 + sl*4;                                          \
    float4 w_r = ld4((WR)+k0), w_z = ld4((WZ)+k0), w_n = ld4((WN)+k0);     \
    _Pragma("unroll")                                                      \
    for (int b=0;b<8;++b) {                                                \
      float4 xv = ld4(Xs + (half*8+b)*1024 + k0);                          \
      ar[b] = dot4(w_r, xv, ar[b]);                                        \
      az[b] = dot4(w_z, xv, az[b]);                                        \
      AN[b] = dot4(w_n, xv, AN[b]);                                        \
    }                                                                      \
  }

  // x-part: w_ih [3*DETER, 1024]
  stage_chunk<JOB_GATES>(p, Xs, 0, kc, t);
  {
    const float* wr = p.w_ih + (size_t)j*1024;
    const float* wz = p.w_ih + (size_t)(DETER_+j)*1024;
    const float* wn = p.w_ih + (size_t)(2*DETER_+j)*1024;
    GATES_INNER(wr, wz, wn, anx)
  }
  // h-part: w_hh [3*DETER, 4096], 4 chunks
  for (int c=1;c<5;++c) {
    stage_chunk<JOB_GATES>(p, Xs, c, kc, t);
    const size_t base = (size_t)(c-1)*1024;
    const float* wr = p.w_hh + (size_t)j*4096 + base;
    const float* wz = p.w_hh + (size_t)(DETER_+j)*4096 + base;
    const float* wn = p.w_hh + (size_t)(2*DETER_+j)*4096 + base;
    GATES_INNER(wr, wz, wn, anh)
  }
#undef GATES_INNER

  // butterfly reduce within each 32-lane half
  #pragma unroll
  for (int off=1; off<32; off<<=1) {
    #pragma unroll
    for (int b=0;b<8;++b) {
      ar[b]  += __shfl_xor(ar[b],  off);
      az[b]  += __shfl_xor(az[b],  off);
      anx[b] += __shfl_xor(anx[b], off);
      anh[b] += __shfl_xor(anh[b], off);
    }
  }
  __syncthreads();   // all Xs reads done -> safe to overlay results
  if (sl==0) {
    #pragma unroll
    for (int b=0;b<8;++b) {
      Xs[(wave*4+0)*16 + half*8 + b] = ar[b];
      Xs[(wave*4+1)*16 + half*8 + b] = az[b];
      Xs[(wave*4+2)*16 + half*8 + b] = anx[b];
      Xs[(wave*4+3)*16 + half*8 + b] = anh[b];
    }
  }
  __syncthreads();

  if (tid < 64) {
    int u = tid&3, b = tid>>2;           // j fast -> 16B-contiguous stores
    int jj = bid*4 + u;
    const float* res = Xs;
    float rs = res[(u*4+0)*16+b] + p.b_ih[jj]          + p.b_hh[jj];
    float zs = res[(u*4+1)*16+b] + p.b_ih[DETER_+jj]   + p.b_hh[DETER_+jj];
    float ni = res[(u*4+2)*16+b] + p.b_ih[2*DETER_+jj];
    float nh = res[(u*4+3)*16+b] + p.b_hh[2*DETER_+jj];
    float rg = sigm(rs), zg = sigm(zs);
    float ng = tanhf(ni + rg*nh);
    float mb = p.is_first[b*T_+t] ? 0.f : 1.f;
    float hp = p.deter_in[b*DETER_+jj] * mb;
    float d  = (1.f-zg)*ng + zg*hp;
    p.deter_out[b*DETER_+jj] = d;
    size_t ob = ((size_t)(b*T_+t))*FOUT_;
    p.out[ob+1536+jj] = d;
    p.out[ob+7168+jj] = d;
  }
}

// ---------------- generic 2-rows-per-wave jobs ----------------
template<int JOB>
__device__ __forceinline__ void mv_body(const SP& p, int bid, float* Xs) {
  constexpr int KTOT = (JOB==JOB_IMGIN)?1024:((JOB==JOB_OBS)?8192:4096);
  constexpr int CHUNKS = KTOT/1024;
  const int tid = threadIdx.x;
  const int wave = tid>>6, lane = tid&63;
  const int half = lane>>5, sl = lane&31;
  const int t = p.t;
  const int kc = tid*4;

  float acc[2][8];
  #pragma unroll
  for (int r=0;r<2;++r)
    #pragma unroll
    for (int b=0;b<8;++b) acc[r][b]=0.f;

  int rowIdx[2];
  #pragma unroll
  for (int r=0;r<2;++r) {
    int rl = wave*2 + r;
    if constexpr (JOB==JOB_IMGIN || JOB==JOB_PRIOR_INIT) rowIdx[r] = bid*8 + rl;
    else rowIdx[r] = (rl<4) ? (bid*4+rl) : (512 + bid*4 + (rl-4));  // mean rows then std rows
  }

  for (int c=0;c<CHUNKS;++c) {
    stage_chunk<JOB>(p, Xs, c, kc, t);
    const float* w0; const float* w1;
    if constexpr (JOB==JOB_IMGIN) {
      w0 = p.wpad_imgin + (size_t)rowIdx[0]*1024;
      w1 = p.wpad_imgin + (size_t)rowIdx[1]*1024;
    } else if constexpr (JOB==JOB_PRIOR || JOB==JOB_PRIOR_INIT) {
      w0 = p.w_imgout + (size_t)rowIdx[0]*4096 + (size_t)c*1024;
      w1 = p.w_imgout + (size_t)rowIdx[1]*4096 + (size_t)c*1024;
    } else {
      w0 = p.w_obs + (size_t)rowIdx[0]*8192 + (size_t)c*1024;
      w1 = p.w_obs + (size_t)rowIdx[1]*8192 + (size_t)c*1024;
    }
    #pragma unroll
    for (int it=0; it<8; ++it) {
      const int k0 = it*128 + sl*4;
      float4 wa = ld4(w0 + k0), wb2 = ld4(w1 + k0);
      #pragma unroll
      for (int b=0;b<8;++b) {
        float4 xv = ld4(Xs + (half*8+b)*1024 + k0);
        acc[0][b] = dot4(wa,  xv, acc[0][b]);
        acc[1][b] = dot4(wb2, xv, acc[1][b]);
      }
    }
  }

  #pragma unroll
  for (int off=1; off<32; off<<=1)
    #pragma unroll
    for (int r=0;r<2;++r)
      #pragma unroll
      for (int b=0;b<8;++b)
        acc[r][b] += __shfl_xor(acc[r][b], off);
  __syncthreads();
  if (sl==0) {
    #pragma unroll
    for (int r=0;r<2;++r)
      #pragma unroll
      for (int b=0;b<8;++b)
        Xs[(wave*2+r)*16 + half*8 + b] = acc[r][b];
  }
  __syncthreads();
  const float* res = Xs;

  if constexpr (JOB==JOB_PRIOR) {
    if (tid < 64) {
      int rl = tid&3, b = tid>>2;
      int j = bid*4 + rl;
      float mean = res[rl*16+b]     + p.b_imgout[j];
      float sr   = res[(rl+4)*16+b] + p.b_imgout[512+j];
      float sd = 2.f*sigm(sr*0.5f) + 0.1f; sd = fmaxf(sd, 1e-4f);
      float ep = p.eps_prior[((size_t)t*B_+b)*STOCH_ + j];
      size_t ob = ((size_t)(b*T_+t))*FOUT_;
      p.out[ob+5632+j] = fmaf(sd, ep, mean);
      p.out[ob+6144+j] = mean;
      p.out[ob+6656+j] = sd;
    }
  } else if constexpr (JOB==JOB_OBS) {
    if (tid < 64) {
      int rl = tid&3, b = tid>>2;
      int j = bid*4 + rl;
      float mean = res[rl*16+b]     + p.b_obs[j];
      float sr   = res[(rl+4)*16+b] + p.b_obs[512+j];
      float sd = 2.f*sigm(sr*0.5f) + 0.1f; sd = fmaxf(sd, 1e-4f);
      float eo = p.eps_post[((size_t)t*B_+b)*STOCH_ + j];
      float ost = fmaf(sd, eo, mean);
      size_t ob = ((size_t)(b*T_+t))*FOUT_;
      p.out[ob+0+j]    = ost;
      p.out[ob+512+j]  = mean;
      p.out[ob+1024+j] = sd;
      p.stoch[b*STOCH_+j] = ost;        // carry for next step
    }
  } else if constexpr (JOB==JOB_IMGIN) {
    if (tid < 128) {
      int rl = tid&7, b = tid>>3;
      int row = bid*8 + rl;
      p.x_img[b*UNITS_+row] = res[rl*16+b] + p.b_imgin[row];
    }
  } else { // JOB_PRIOR_INIT: stoch0 = mean part only
    if (tid < 128) {
      int rl = tid&7, b = tid>>3;
      int row = bid*8 + rl;          // row < 512 (mean rows)
      p.stoch[b*STOCH_+row] = res[rl*16+b] + p.b_imgout[row];
    }
  }
}

__global__ __launch_bounds__(256,2) void gates_kernel(SP p) {
  __shared__ float Xs[16*1024];
  gates_body(p, blockIdx.x, Xs);
}

template<int JOB>
__global__ __launch_bounds__(256,2) void mv_single(SP p) {
  __shared__ float Xs[16*1024];
  mv_body<JOB>(p, blockIdx.x, Xs);
}

// prior (128 blocks) + obs (128 blocks) in one launch
__global__ __launch_bounds__(256,2) void post_kernel(SP p) {
  __shared__ float Xs[16*1024];
  if (blockIdx.x < 128) mv_body<JOB_PRIOR>(p, blockIdx.x, Xs);
  else                  mv_body<JOB_OBS>(p, blockIdx.x - 128, Xs);
}

__global__ void pad_imgin_kernel(const float* w, float* wpad) {
  int row = blockIdx.x;
  for (int k=threadIdx.x; k<1024; k+=256)
    wpad[row*1024+k] = (k<514) ? w[row*514+k] : 0.f;
}

__global__ void init_deter_kernel(const float* ini, float* det) {
  int k = blockIdx.x*256 + threadIdx.x;
  float v = tanhf(ini[k]);
  #pragma unroll
  for (int b=0;b<16;++b) det[b*DETER_+k] = v;
}

extern "C" void kernel_launch(void* const* d_in, const int* in_sizes, int n_in,
                              void* d_out, int out_size, void* d_ws, size_t ws_size,
                              hipStream_t stream) {
  (void)in_sizes; (void)n_in; (void)out_size; (void)ws_size;
  SP p;
  p.embed     = (const float*)d_in[0];
  p.action    = (const float*)d_in[1];
  p.is_first  = (const int*)  d_in[2];
  const float* initial_deter = (const float*)d_in[3];
  p.w_obs     = (const float*)d_in[4];
  p.b_obs     = (const float*)d_in[5];
  const float* w_imgin       = (const float*)d_in[6];
  p.b_imgin   = (const float*)d_in[7];
  p.w_imgout  = (const float*)d_in[8];
  p.b_imgout  = (const float*)d_in[9];
  p.w_ih      = (const float*)d_in[10];
  p.w_hh      = (const float*)d_in[11];
  p.b_ih      = (const float*)d_in[12];
  p.b_hh      = (const float*)d_in[13];
  p.eps_prior = (const float*)d_in[14];
  p.eps_post  = (const float*)d_in[15];
  p.out = (float*)d_out;

  // ws layout (floats): wpad 1M | deterA 64K | deterB 64K | stoch 8K | x_img 16K  (~4.8 MB)
  float* ws     = (float*)d_ws;
  float* wpad   = ws;
  float* deterA = wpad   + 1024*1024;
  float* deterB = deterA + 16*DETER_;
  float* stoch  = deterB + 16*DETER_;
  float* ximg   = stoch  + 16*STOCH_;
  p.wpad_imgin = wpad;
  p.stoch = stoch;
  p.x_img = ximg;

  pad_imgin_kernel<<<1024,256,0,stream>>>(w_imgin, wpad);
  init_deter_kernel<<<DETER_/256,256,0,stream>>>(initial_deter, deterA);

  // stoch0 = mean(stats(deter0 @ w_imgout.T + b))
  p.t = 0; p.deter_in = deterA; p.deter_out = deterB; p.dnew = deterA;
  mv_single<JOB_PRIOR_INIT><<<64,256,0,stream>>>(p);

  for (int t=0; t<T_; ++t) {
    p.t = t;
    p.deter_in  = (t&1) ? deterB : deterA;
    p.deter_out = (t&1) ? deterA : deterB;
    p.dnew      = p.deter_out;
    mv_single<JOB_IMGIN><<<128,256,0,stream>>>(p);   // x_img = imgin(concat(stoch_m, a_m))
    gates_kernel<<<1024,256,0,stream>>>(p);          // GRU fused: gi,gh matmuls + gates + d_new (+out copies)
    post_kernel<<<256,256,0,stream>>>(p);            // prior + obs matmuls + stats + rsample + out
  }
}

// Round 3
// 10968.478 us; speedup vs baseline: 2.5205x; 1.3918x over previous
//
#include <hip/hip_runtime.h>
#include <math.h>

#define B_ 16
#define T_ 64
#define DETER_ 4096
#define STOCH_ 512
#define UNITS_ 1024
#define EMBED_ 4096
#define FOUT_ 11264

enum { JOB_IMGIN=0, JOB_GATES=1, JOB_PRIOR=2, JOB_OBS=3, JOB_PRIOR_INIT=4 };

struct SP {
  const float* embed; const float* action; const int* is_first;
  const float* wpad_imgin; const float* b_imgin;
  const float* w_ih; const float* w_hh; const float* b_ih; const float* b_hh;
  const float* w_imgout; const float* b_imgout;
  const float* w_obs; const float* b_obs;
  const float* eps_prior; const float* eps_post;
  const float* deter_m_in;    // masked prev deter (read by gates)
  float*       deter_m_out;   // masked new deter for next step
  float*       dnew;          // unmasked new deter (read by post, written by gates)
  float* stoch_m; float* x_img; float* out;
  int t;
};

__device__ __forceinline__ float4 ld4(const float* p){ return *reinterpret_cast<const float4*>(p); }
__device__ __forceinline__ float sigm(float x){ return 1.f/(1.f+expf(-x)); }
__device__ __forceinline__ float dot4(float4 w, float4 x, float a){
  return fmaf(w.x,x.x, fmaf(w.y,x.y, fmaf(w.z,x.z, fmaf(w.w,x.w, a))));
}

// Direct global->LDS DMA, 16B per lane. LDS dest must be wave-uniform base
// (HW adds lane*16); global src is per-lane. Zero VGPR cost -> no spill
// pressure around staging (the R2 bug: 194MB of accumulator spill traffic).
__device__ __forceinline__ void g2l16(const float* g, float* l) {
  __builtin_amdgcn_global_load_lds(
      (const __attribute__((address_space(1))) unsigned int*)g,
      (__attribute__((address_space(3))) unsigned int*)l, 16, 0, 0);
}

// Stage one 1024-float K-chunk of X for all 16 batches into LDS.
// Wave w stages batch rows w*4..w*4+3; each row = SEGS segments of 256 floats
// (64 lanes x 16B). All sources are pure linear copies (masking pre-applied).
template<int JOB>
__device__ __forceinline__ void stage_async(const SP& p, float* Xs, int c,
                                            int wave, int lane, int tid, int t) {
  __syncthreads();   // previous chunk's readers done
  constexpr int SEGS = (JOB==JOB_IMGIN) ? 2 : 4;
  #pragma unroll
  for (int q=0;q<4;++q) {
    const int b = wave*4+q;
    const float* src;
    if constexpr (JOB==JOB_GATES)
      src = (c==0) ? (p.x_img + b*UNITS_) : (p.deter_m_in + b*DETER_ + (c-1)*1024);
    else if constexpr (JOB==JOB_PRIOR || JOB==JOB_PRIOR_INIT)
      src = p.dnew + b*DETER_ + c*1024;
    else if constexpr (JOB==JOB_OBS)
      src = (c<4) ? (p.dnew + b*DETER_ + c*1024)
                  : (p.embed + ((size_t)(b*T_+t))*EMBED_ + (c-4)*1024);
    else // JOB_IMGIN: lower 512 = pre-masked stoch
      src = p.stoch_m + b*STOCH_;
    float* dst = Xs + b*1024;
    #pragma unroll
    for (int seg=0;seg<SEGS;++seg)
      g2l16(src + seg*256 + lane*4, dst + seg*256);
  }
  if constexpr (JOB==JOB_IMGIN) {
    // upper 512 floats: action (2 real values) + zero pad, written directly
    const int kc = tid*4;
    if (kc >= 512) {
      #pragma unroll
      for (int b=0;b<16;++b) {
        float4 v = make_float4(0.f,0.f,0.f,0.f);
        if (kc == 512) {
          float mb = p.is_first[b*T_+t] ? 0.f : 1.f;
          const float* ap = p.action + (b*T_+t)*2;
          float a0 = ap[0], a1 = ap[1];
          v.x = (a0 / fmaxf(fabsf(a0),1.f))*mb;   // ACTION_CLIP=1
          v.y = (a1 / fmaxf(fabsf(a1),1.f))*mb;
        }
        *reinterpret_cast<float4*>(Xs + b*1024 + kc) = v;
      }
    }
  }
  __syncthreads();   // drains vmcnt (global_load_lds) before compute
}

// ---------------- GATES: GRU fused ----------------
// Block = 256 thr / 4 waves; wave owns unit j = bid*4 + wave (3 gate rows).
// Lanes 0-31 accumulate batches 0-7, lanes 32-63 batches 8-15.
__device__ __forceinline__ void gates_body(const SP& p, int bid, float* Xs) {
  const int tid = threadIdx.x;
  const int wave = tid>>6, lane = tid&63;
  const int half = lane>>5, sl = lane&31;
  const int t = p.t;
  const int j = bid*4 + wave;

  float ar[8], az[8], anx[8], anh[8];
  #pragma unroll
  for (int b=0;b<8;++b){ ar[b]=0.f; az[b]=0.f; anx[b]=0.f; anh[b]=0.f; }

#define GATES_INNER(WR,WZ,WN,AN)                                           \
  _Pragma("unroll")                                                        \
  for (int it=0; it<8; ++it) {                                             \
    const int k0 = it*128 + sl*4;                                          \
    float4 w_r = ld4((WR)+k0), w_z = ld4((WZ)+k0), w_n = ld4((WN)+k0);     \
    _Pragma("unroll")                                                      \
    for (int b=0;b<8;++b) {                                                \
      float4 xv = ld4(Xs + (half*8+b)*1024 + k0);                          \
      ar[b] = dot4(w_r, xv, ar[b]);                                        \
      az[b] = dot4(w_z, xv, az[b]);                                        \
      AN[b] = dot4(w_n, xv, AN[b]);                                        \
    }                                                                      \
  }

  // x-part: w_ih [3*DETER, 1024]
  stage_async<JOB_GATES>(p, Xs, 0, wave, lane, tid, t);
  {
    const float* wr = p.w_ih + (size_t)j*1024;
    const float* wz = p.w_ih + (size_t)(DETER_+j)*1024;
    const float* wn = p.w_ih + (size_t)(2*DETER_+j)*1024;
    GATES_INNER(wr, wz, wn, anx)
  }
  // h-part: w_hh [3*DETER, 4096], 4 chunks
  for (int c=1;c<5;++c) {
    stage_async<JOB_GATES>(p, Xs, c, wave, lane, tid, t);
    const size_t base = (size_t)(c-1)*1024;
    const float* wr = p.w_hh + (size_t)j*4096 + base;
    const float* wz = p.w_hh + (size_t)(DETER_+j)*4096 + base;
    const float* wn = p.w_hh + (size_t)(2*DETER_+j)*4096 + base;
    GATES_INNER(wr, wz, wn, anh)
  }
#undef GATES_INNER

  // butterfly reduce within each 32-lane half
  #pragma unroll
  for (int off=1; off<32; off<<=1) {
    #pragma unroll
    for (int b=0;b<8;++b) {
      ar[b]  += __shfl_xor(ar[b],  off);
      az[b]  += __shfl_xor(az[b],  off);
      anx[b] += __shfl_xor(anx[b], off);
      anh[b] += __shfl_xor(anh[b], off);
    }
  }
  __syncthreads();   // all Xs reads done -> safe to overlay results
  if (sl==0) {
    #pragma unroll
    for (int b=0;b<8;++b) {
      Xs[(wave*4+0)*16 + half*8 + b] = ar[b];
      Xs[(wave*4+1)*16 + half*8 + b] = az[b];
      Xs[(wave*4+2)*16 + half*8 + b] = anx[b];
      Xs[(wave*4+3)*16 + half*8 + b] = anh[b];
    }
  }
  __syncthreads();

  if (tid < 64) {
    int u = tid&3, b = tid>>2;           // j fast -> 16B-contiguous stores
    int jj = bid*4 + u;
    const float* res = Xs;
    float rs = res[(u*4+0)*16+b] + p.b_ih[jj]          + p.b_hh[jj];
    float zs = res[(u*4+1)*16+b] + p.b_ih[DETER_+jj]   + p.b_hh[DETER_+jj];
    float ni = res[(u*4+2)*16+b] + p.b_ih[2*DETER_+jj];
    float nh = res[(u*4+3)*16+b] + p.b_hh[2*DETER_+jj];
    float rg = sigm(rs), zg = sigm(zs);
    float ng = tanhf(ni + rg*nh);
    float hp = p.deter_m_in[b*DETER_+jj];          // already masked
    float d  = (1.f-zg)*ng + zg*hp;
    p.dnew[b*DETER_+jj] = d;
    int tn = t+1;
    float mb2 = (tn<T_) ? (p.is_first[b*T_+tn] ? 0.f : 1.f) : 0.f;
    p.deter_m_out[b*DETER_+jj] = d*mb2;            // pre-masked for next step
    size_t ob = ((size_t)(b*T_+t))*FOUT_;
    p.out[ob+1536+jj] = d;
    p.out[ob+7168+jj] = d;
  }
}

// ---------------- generic 2-rows-per-wave jobs ----------------
template<int JOB>
__device__ __forceinline__ void mv_body(const SP& p, int bid, float* Xs) {
  constexpr int KTOT = (JOB==JOB_IMGIN)?1024:((JOB==JOB_OBS)?8192:4096);
  constexpr int CHUNKS = KTOT/1024;
  const int tid = threadIdx.x;
  const int wave = tid>>6, lane = tid&63;
  const int half = lane>>5, sl = lane&31;
  const int t = p.t;

  float acc[2][8];
  #pragma unroll
  for (int r=0;r<2;++r)
    #pragma unroll
    for (int b=0;b<8;++b) acc[r][b]=0.f;

  int rowIdx[2];
  #pragma unroll
  for (int r=0;r<2;++r) {
    int rl = wave*2 + r;
    if constexpr (JOB==JOB_IMGIN || JOB==JOB_PRIOR_INIT) rowIdx[r] = bid*8 + rl;
    else rowIdx[r] = (rl<4) ? (bid*4+rl) : (512 + bid*4 + (rl-4));  // mean rows then std rows
  }

  for (int c=0;c<CHUNKS;++c) {
    stage_async<JOB>(p, Xs, c, wave, lane, tid, t);
    const float* w0; const float* w1;
    if constexpr (JOB==JOB_IMGIN) {
      w0 = p.wpad_imgin + (size_t)rowIdx[0]*1024;
      w1 = p.wpad_imgin + (size_t)rowIdx[1]*1024;
    } else if constexpr (JOB==JOB_PRIOR || JOB==JOB_PRIOR_INIT) {
      w0 = p.w_imgout + (size_t)rowIdx[0]*4096 + (size_t)c*1024;
      w1 = p.w_imgout + (size_t)rowIdx[1]*4096 + (size_t)c*1024;
    } else {
      w0 = p.w_obs + (size_t)rowIdx[0]*8192 + (size_t)c*1024;
      w1 = p.w_obs + (size_t)rowIdx[1]*8192 + (size_t)c*1024;
    }
    #pragma unroll
    for (int it=0; it<8; ++it) {
      const int k0 = it*128 + sl*4;
      float4 wa = ld4(w0 + k0), wb2 = ld4(w1 + k0);
      #pragma unroll
      for (int b=0;b<8;++b) {
        float4 xv = ld4(Xs + (half*8+b)*1024 + k0);
        acc[0][b] = dot4(wa,  xv, acc[0][b]);
        acc[1][b] = dot4(wb2, xv, acc[1][b]);
      }
    }
  }

  #pragma unroll
  for (int off=1; off<32; off<<=1)
    #pragma unroll
    for (int r=0;r<2;++r)
      #pragma unroll
      for (int b=0;b<8;++b)
        acc[r][b] += __shfl_xor(acc[r][b], off);
  __syncthreads();
  if (sl==0) {
    #pragma unroll
    for (int r=0;r<2;++r)
      #pragma unroll
      for (int b=0;b<8;++b)
        Xs[(wave*2+r)*16 + half*8 + b] = acc[r][b];
  }
  __syncthreads();
  const float* res = Xs;

  if constexpr (JOB==JOB_PRIOR) {
    if (tid < 64) {
      int rl = tid&3, b = tid>>2;
      int j = bid*4 + rl;
      float mean = res[rl*16+b]     + p.b_imgout[j];
      float sr   = res[(rl+4)*16+b] + p.b_imgout[512+j];
      float sd = 2.f*sigm(sr*0.5f) + 0.1f; sd = fmaxf(sd, 1e-4f);
      float ep = p.eps_prior[((size_t)t*B_+b)*STOCH_ + j];
      size_t ob = ((size_t)(b*T_+t))*FOUT_;
      p.out[ob+5632+j] = fmaf(sd, ep, mean);
      p.out[ob+6144+j] = mean;
      p.out[ob+6656+j] = sd;
    }
  } else if constexpr (JOB==JOB_OBS) {
    if (tid < 64) {
      int rl = tid&3, b = tid>>2;
      int j = bid*4 + rl;
      float mean = res[rl*16+b]     + p.b_obs[j];
      float sr   = res[(rl+4)*16+b] + p.b_obs[512+j];
      float sd = 2.f*sigm(sr*0.5f) + 0.1f; sd = fmaxf(sd, 1e-4f);
      float eo = p.eps_post[((size_t)t*B_+b)*STOCH_ + j];
      float ost = fmaf(sd, eo, mean);
      size_t ob = ((size_t)(b*T_+t))*FOUT_;
      p.out[ob+0+j]    = ost;
      p.out[ob+512+j]  = mean;
      p.out[ob+1024+j] = sd;
      int tn = t+1;
      float mb2 = (tn<T_) ? (p.is_first[b*T_+tn] ? 0.f : 1.f) : 0.f;
      p.stoch_m[b*STOCH_+j] = ost*mb2;     // pre-masked carry for next step
    }
  } else if constexpr (JOB==JOB_IMGIN) {
    if (tid < 128) {
      int rl = tid&7, b = tid>>3;
      int row = bid*8 + rl;
      p.x_img[b*UNITS_+row] = res[rl*16+b] + p.b_imgin[row];
    }
  } else { // JOB_PRIOR_INIT: stoch0 = mean part, pre-masked with mask(0)
    if (tid < 128) {
      int rl = tid&7, b = tid>>3;
      int row = bid*8 + rl;          // row < 512 (mean rows)
      float mean = res[rl*16+b] + p.b_imgout[row];
      float mb = p.is_first[b*T_+0] ? 0.f : 1.f;
      p.stoch_m[b*STOCH_+row] = mean*mb;
    }
  }
}

__global__ __launch_bounds__(256,2) void gates_kernel(SP p) {
  __shared__ float Xs[16*1024];
  gates_body(p, blockIdx.x, Xs);
}

template<int JOB>
__global__ __launch_bounds__(256,2) void mv_single(SP p) {
  __shared__ float Xs[16*1024];
  mv_body<JOB>(p, blockIdx.x, Xs);
}

// prior (128 blocks) + obs (128 blocks) in one launch
__global__ __launch_bounds__(256,2) void post_kernel(SP p) {
  __shared__ float Xs[16*1024];
  if (blockIdx.x < 128) mv_body<JOB_PRIOR>(p, blockIdx.x, Xs);
  else                  mv_body<JOB_OBS>(p, blockIdx.x - 128, Xs);
}

__global__ void pad_imgin_kernel(const float* w, float* wpad) {
  int row = blockIdx.x;
  for (int k=threadIdx.x; k<1024; k+=256)
    wpad[row*1024+k] = (k<514) ? w[row*514+k] : 0.f;
}

// deterA = tanh(initial) broadcast; deter_m(0) = deterA * mask(0)
__global__ void init_deter_kernel(const float* ini, float* det, float* detm,
                                  const int* is_first) {
  int k = blockIdx.x*256 + threadIdx.x;
  float v = tanhf(ini[k]);
  #pragma unroll
  for (int b=0;b<16;++b) {
    det[b*DETER_+k] = v;
    float mb = is_first[b*T_+0] ? 0.f : 1.f;
    detm[b*DETER_+k] = v*mb;
  }
}

extern "C" void kernel_launch(void* const* d_in, const int* in_sizes, int n_in,
                              void* d_out, int out_size, void* d_ws, size_t ws_size,
                              hipStream_t stream) {
  (void)in_sizes; (void)n_in; (void)out_size; (void)ws_size;
  SP p;
  p.embed     = (const float*)d_in[0];
  p.action    = (const float*)d_in[1];
  p.is_first  = (const int*)  d_in[2];
  const float* initial_deter = (const float*)d_in[3];
  p.w_obs     = (const float*)d_in[4];
  p.b_obs     = (const float*)d_in[5];
  const float* w_imgin       = (const float*)d_in[6];
  p.b_imgin   = (const float*)d_in[7];
  p.w_imgout  = (const float*)d_in[8];
  p.b_imgout  = (const float*)d_in[9];
  p.w_ih      = (const float*)d_in[10];
  p.w_hh      = (const float*)d_in[11];
  p.b_ih      = (const float*)d_in[12];
  p.b_hh      = (const float*)d_in[13];
  p.eps_prior = (const float*)d_in[14];
  p.eps_post  = (const float*)d_in[15];
  p.out = (float*)d_out;

  // ws layout (floats): wpad 1M | dnew 64K | deterM0 64K | deterM1 64K | stoch_m 8K | x_img 16K
  float* ws      = (float*)d_ws;
  float* wpad    = ws;
  float* dnew    = wpad    + 1024*1024;
  float* deterM0 = dnew    + 16*DETER_;
  float* deterM1 = deterM0 + 16*DETER_;
  float* stochm  = deterM1 + 16*DETER_;
  float* ximg    = stochm  + 16*STOCH_;
  p.wpad_imgin = wpad;
  p.stoch_m = stochm;
  p.x_img = ximg;

  pad_imgin_kernel<<<1024,256,0,stream>>>(w_imgin, wpad);
  init_deter_kernel<<<DETER_/256,256,0,stream>>>(initial_deter, dnew, deterM0, p.is_first);

  // stoch0 = mean(stats(deter0 @ w_imgout.T + b)) * mask(0)   (dnew == tanh(deter0) here)
  p.t = 0; p.dnew = dnew; p.deter_m_in = deterM0; p.deter_m_out = deterM1;
  mv_single<JOB_PRIOR_INIT><<<64,256,0,stream>>>(p);

  for (int t=0; t<T_; ++t) {
    p.t = t;
    p.deter_m_in  = (t&1) ? deterM1 : deterM0;
    p.deter_m_out = (t&1) ? deterM0 : deterM1;
    p.dnew        = dnew;
    mv_single<JOB_IMGIN><<<128,256,0,stream>>>(p);   // x_img = imgin(concat(stoch_m, a_m))
    gates_kernel<<<1024,256,0,stream>>>(p);          // GRU fused: gi,gh matmuls + gates + d_new (+out copies)
    post_kernel<<<256,256,0,stream>>>(p);            // prior + obs matmuls + stats + rsample + out
  }
}